// Round 5
// baseline (124.312 us; speedup 1.0000x reference)
//
#include <hip/hip_runtime.h>

#define IN_DIM 4096
#define N_SOMA 16384
#define N_NEURONS 1024
#define BATCH 256
#define NEG_SLOPE 0.1f

typedef float f32x4 __attribute__((ext_vector_type(4)));

// ---------------------------------------------------------------------------
// Kernel 1: transpose x [BATCH][IN_DIM] -> xT [IN_DIM][BATCH]
// ---------------------------------------------------------------------------
__global__ __launch_bounds__(256) void transpose_x_kernel(
    const float* __restrict__ x, float* __restrict__ xT) {
    __shared__ float tile[64][65];
    const int i0 = blockIdx.x * 64;
    const int b0 = blockIdx.y * 64;
    const int lane = threadIdx.x & 63;
    const int grp  = threadIdx.x >> 6;

#pragma unroll
    for (int r = 0; r < 16; ++r) {
        const int b_local = grp * 16 + r;
        tile[b_local][lane] = x[(size_t)(b0 + b_local) * IN_DIM + i0 + lane];
    }
    __syncthreads();
#pragma unroll
    for (int r = 0; r < 16; ++r) {
        const int i_local = grp * 16 + r;
        xT[(size_t)(i0 + i_local) * BATCH + b0 + lane] = tile[lane][i_local];
    }
}

// ---------------------------------------------------------------------------
// Kernel 2: fused, barrier-free main loop. One block per neuron; wave w owns
// dendrite rows {w, w+4, w+8, w+12} END-TO-END: stream row from HBM ->
// ballot-compact into wave-private LDS (double-buffered by row parity) ->
// 32 pairs x 4 batch-quarters of L2 gathers+FMAs for ALL 256 batch columns.
// Waves never sync in the loop, so per-CU some waves always have HBM loads
// outstanding while others gather from L2 -> stream/compute overlap.
// Final: one barrier + 4-way partial-sum reduction + soma LeakyReLU.
// ---------------------------------------------------------------------------
__global__ __launch_bounds__(256, 4) void fused_kernel(
    const float* __restrict__ dW, const float* __restrict__ db,
    const float* __restrict__ sW, const float* __restrict__ sb,
    const float* __restrict__ xT, float* __restrict__ out) {
    const int bid = blockIdx.x;
    // XCD-chunked swizzle: 128 consecutive neurons per XCD -> output-column
    // write merging and xT residency within one L2.
    const int n = (bid & 7) * (N_NEURONS / 8) + (bid >> 3);
    const int t = threadIdx.x;
    const int wave = t >> 6;
    const int lane = t & 63;
    const unsigned long long lt = (1ull << lane) - 1ull;

    __shared__ int2  s_pair[2][4][32];   // [parity][wave][pos] = (idx*BATCH, w)
    __shared__ float s_part[4][BATCH];   // per-wave partial soma sums

    float psum[4] = {0.f, 0.f, 0.f, 0.f};

    for (int rr = 0; rr < 4; ++rr) {
        const int r = rr * 4 + wave;  // this wave's dendrite row (0..15)
        const f32x4* row4 = reinterpret_cast<const f32x4*>(
            dW + (size_t)(n * 16 + r) * IN_DIM);
        f32x4 v[16];
#pragma unroll
        for (int k = 0; k < 16; ++k)
            v[k] = __builtin_nontemporal_load(row4 + k * 64 + lane);

        // Deterministic in-wave compaction, order = ascending global index.
        int2* pair = s_pair[rr & 1][wave];
        int base = 0;
#pragma unroll
        for (int k = 0; k < 16; ++k) {
            float e[4] = {v[k].x, v[k].y, v[k].z, v[k].w};
            unsigned long long m[4];
#pragma unroll
            for (int c = 0; c < 4; ++c) m[c] = __ballot(e[c] != 0.f);
            int below = 0;
#pragma unroll
            for (int c = 0; c < 4; ++c) below += __popcll(m[c] & lt);
            int myprev = 0;
#pragma unroll
            for (int c = 0; c < 4; ++c) {
                if (e[c] != 0.f) {
                    const int pos = base + below + myprev;
                    if (pos < 32)
                        pair[pos] = make_int2((((k * 64 + lane) << 2) + c) << 8,
                                              __float_as_int(e[c]));
                    ++myprev;
                }
            }
#pragma unroll
            for (int c = 0; c < 4; ++c) base += __popcll(m[c]);
        }

        const float sw  = sW[(size_t)n * N_SOMA + n * 16 + r];
        const float dbr = db[n * 16 + r];
        float dacc[4] = {dbr, dbr, dbr, dbr};
#pragma unroll
        for (int j = 0; j < 32; ++j) {
            const int2 p = pair[j];                 // broadcast LDS read
            const float w = __int_as_float(p.y);
            const float* src = xT + p.x + lane;
#pragma unroll
            for (int q = 0; q < 4; ++q)             // coalesced 256B gathers
                dacc[q] = fmaf(w, src[q * 64], dacc[q]);
        }
#pragma unroll
        for (int q = 0; q < 4; ++q) {
            const float dr = (dacc[q] >= 0.f) ? dacc[q] : NEG_SLOPE * dacc[q];
            psum[q] = fmaf(sw, dr, psum[q]);
        }
    }

#pragma unroll
    for (int q = 0; q < 4; ++q)
        s_part[wave][q * 64 + lane] = psum[q];
    __syncthreads();

    float sacc = sb[n] + s_part[0][t] + s_part[1][t] + s_part[2][t] + s_part[3][t];
    sacc = (sacc >= 0.f) ? sacc : NEG_SLOPE * sacc;
    out[(size_t)t * N_NEURONS + n] = sacc;
}

// ---------------------------------------------------------------------------
extern "C" void kernel_launch(void* const* d_in, const int* in_sizes, int n_in,
                              void* d_out, int out_size, void* d_ws, size_t ws_size,
                              hipStream_t stream) {
    const float* x  = (const float*)d_in[0];  // [256][4096]
    const float* dW = (const float*)d_in[1];  // [16384][4096] (pre-masked)
    const float* db = (const float*)d_in[2];  // [16384]
    const float* sW = (const float*)d_in[3];  // [1024][16384] (pre-masked)
    const float* sb = (const float*)d_in[4];  // [1024]
    float* out = (float*)d_out;               // [256][1024]

    float* xT = (float*)d_ws;                 // [4096][256]  4 MB

    transpose_x_kernel<<<dim3(IN_DIM / 64, BATCH / 64), 256, 0, stream>>>(x, xT);
    fused_kernel<<<N_NEURONS, 256, 0, stream>>>(dW, db, sW, sb, xT, out);
}

// Round 6
// 104.679 us; speedup vs baseline: 1.1876x; 1.1876x over previous
//
#include <hip/hip_runtime.h>

#define IN_DIM 4096
#define N_SOMA 16384
#define N_NEURONS 1024
#define BATCH 256
#define NEG_SLOPE 0.1f

typedef float f32x4 __attribute__((ext_vector_type(4)));

// ---------------------------------------------------------------------------
// Kernel 1: transpose x [BATCH][IN_DIM] -> xT [IN_DIM][BATCH]
// ---------------------------------------------------------------------------
__global__ __launch_bounds__(256) void transpose_x_kernel(
    const float* __restrict__ x, float* __restrict__ xT) {
    __shared__ float tile[64][65];
    const int i0 = blockIdx.x * 64;
    const int b0 = blockIdx.y * 64;
    const int lane = threadIdx.x & 63;
    const int grp  = threadIdx.x >> 6;

#pragma unroll
    for (int r = 0; r < 16; ++r) {
        const int b_local = grp * 16 + r;
        tile[b_local][lane] = x[(size_t)(b0 + b_local) * IN_DIM + i0 + lane];
    }
    __syncthreads();
#pragma unroll
    for (int r = 0; r < 16; ++r) {
        const int i_local = grp * 16 + r;
        xT[(size_t)(i0 + i_local) * BATCH + b0 + lane] = tile[lane][i_local];
    }
}

// ---------------------------------------------------------------------------
// Kernel 2: fused with PRODUCER/CONSUMER wave specialization.
// Block = 1 neuron, 512 threads (8 waves).
//   Waves 0-3 (producers): stream the neuron's 16 dendrite rows from HBM
//     (nontemporal), ballot-compact each into s_pair[r][32], release-store
//     s_flag[r]. Producers never touch the gather path -> the per-CU HBM
//     load queue never drains.
//   Waves 4-7 (consumers): thread = batch column. For r = 0..15: acquire-
//     spin on s_flag[r], then 32 L3 gathers + FMAs, LeakyReLU, soma FMA.
// The HBM-stream pipe and the L2/L3-gather pipe run CONCURRENTLY on every
// CU (separate waves -> no shared dependence chain, no regs across sync).
// ---------------------------------------------------------------------------
__global__ __launch_bounds__(512, 2) void fused_pc_kernel(
    const float* __restrict__ dW, const float* __restrict__ db,
    const float* __restrict__ sW, const float* __restrict__ sb,
    const float* __restrict__ xT, float* __restrict__ out) {
    const int bid = blockIdx.x;
    // XCD-chunked swizzle (1024 % 8 == 0, bijective): 128 consecutive
    // neurons per XCD -> output write merging + xT locality in one L2.
    const int n = (bid & 7) * (N_NEURONS / 8) + (bid >> 3);
    const int t = threadIdx.x;
    const int wave = t >> 6;
    const int lane = t & 63;

    __shared__ int2 s_pair[16][32];   // (idx*BATCH, float-bits weight)
    __shared__ int  s_flag[16];

    if (t < 16) s_flag[t] = 0;
    __syncthreads();

    if (wave < 4) {
        // ---- producer: rows {wave, wave+4, wave+8, wave+12} ----
        const unsigned long long lt = (1ull << lane) - 1ull;
        for (int rr = 0; rr < 4; ++rr) {
            const int r = rr * 4 + wave;  // rows 0..3 ready first
            const f32x4* row4 = reinterpret_cast<const f32x4*>(
                dW + (size_t)(n * 16 + r) * IN_DIM);
            f32x4 v[16];
#pragma unroll
            for (int k = 0; k < 16; ++k)
                v[k] = __builtin_nontemporal_load(row4 + k * 64 + lane);

            // Deterministic compaction, order = ascending global index.
            int base = 0;
#pragma unroll
            for (int k = 0; k < 16; ++k) {
                float e[4] = {v[k].x, v[k].y, v[k].z, v[k].w};
                unsigned long long m[4];
#pragma unroll
                for (int c = 0; c < 4; ++c) m[c] = __ballot(e[c] != 0.f);
                int below = 0;
#pragma unroll
                for (int c = 0; c < 4; ++c) below += __popcll(m[c] & lt);
                int myprev = 0;
#pragma unroll
                for (int c = 0; c < 4; ++c) {
                    if (e[c] != 0.f) {
                        const int pos = base + below + myprev;
                        if (pos < 32)
                            s_pair[r][pos] =
                                make_int2((((k * 64 + lane) << 2) + c) << 8,
                                          __float_as_int(e[c]));
                        ++myprev;
                    }
                }
#pragma unroll
                for (int c = 0; c < 4; ++c) base += __popcll(m[c]);
            }
            __threadfence_block();  // pairs visible before flag
            if (lane == 0)
                __hip_atomic_store(&s_flag[r], 1, __ATOMIC_RELEASE,
                                   __HIP_MEMORY_SCOPE_WORKGROUP);
        }
    } else {
        // ---- consumer: thread = batch column c ----
        const int c = t - 256;
        float sacc = sb[n];
        for (int r = 0; r < 16; ++r) {
            while (__hip_atomic_load(&s_flag[r], __ATOMIC_ACQUIRE,
                                     __HIP_MEMORY_SCOPE_WORKGROUP) == 0)
                __builtin_amdgcn_s_sleep(1);
            const float sw  = sW[(size_t)n * N_SOMA + n * 16 + r];
            float dacc = db[n * 16 + r];
#pragma unroll
            for (int j = 0; j < 32; ++j) {
                const int2 p = s_pair[r][j];          // broadcast LDS read
                dacc = fmaf(__int_as_float(p.y), xT[p.x + c], dacc);
            }
            dacc = (dacc >= 0.f) ? dacc : NEG_SLOPE * dacc;
            sacc = fmaf(sw, dacc, sacc);
        }
        sacc = (sacc >= 0.f) ? sacc : NEG_SLOPE * sacc;
        out[(size_t)c * N_NEURONS + n] = sacc;
    }
}

// ---------------------------------------------------------------------------
extern "C" void kernel_launch(void* const* d_in, const int* in_sizes, int n_in,
                              void* d_out, int out_size, void* d_ws, size_t ws_size,
                              hipStream_t stream) {
    const float* x  = (const float*)d_in[0];  // [256][4096]
    const float* dW = (const float*)d_in[1];  // [16384][4096] (pre-masked)
    const float* db = (const float*)d_in[2];  // [16384]
    const float* sW = (const float*)d_in[3];  // [1024][16384] (pre-masked)
    const float* sb = (const float*)d_in[4];  // [1024]
    float* out = (float*)d_out;               // [256][1024]

    float* xT = (float*)d_ws;                 // [4096][256]  4 MB

    transpose_x_kernel<<<dim3(IN_DIM / 64, BATCH / 64), 256, 0, stream>>>(x, xT);
    fused_pc_kernel<<<N_NEURONS, 512, 0, stream>>>(dW, db, sW, sb, xT, out);
}

// Round 7
// 92.236 us; speedup vs baseline: 1.3478x; 1.1349x over previous
//
#include <hip/hip_runtime.h>

#define IN_DIM 4096
#define N_SOMA 16384
#define N_NEURONS 1024
#define BATCH 256
#define NEG_SLOPE 0.1f

typedef float f32x4 __attribute__((ext_vector_type(4)));

// ---------------------------------------------------------------------------
// Kernel 1: transpose x [BATCH][IN_DIM] -> xT [IN_DIM][BATCH]
// ---------------------------------------------------------------------------
__global__ __launch_bounds__(256) void transpose_x_kernel(
    const float* __restrict__ x, float* __restrict__ xT) {
    __shared__ float tile[64][65];
    const int i0 = blockIdx.x * 64;
    const int b0 = blockIdx.y * 64;
    const int lane = threadIdx.x & 63;
    const int grp  = threadIdx.x >> 6;

#pragma unroll
    for (int r = 0; r < 16; ++r) {
        const int b_local = grp * 16 + r;
        tile[b_local][lane] = x[(size_t)(b0 + b_local) * IN_DIM + i0 + lane];
    }
    __syncthreads();
#pragma unroll
    for (int r = 0; r < 16; ++r) {
        const int i_local = grp * 16 + r;
        xT[(size_t)(i0 + i_local) * BATCH + b0 + lane] = tile[lane][i_local];
    }
}

// ---------------------------------------------------------------------------
// Kernel 2: streaming sparse compaction, 2-deep software pipeline.
// Each wave owns 4 consecutive rows. Row r+1's 16 loads are ISSUED before
// row r is compacted, so every wave keeps >=16 HBM loads in flight through
// the ~1400-cycle compaction (R2's version drained to zero -> ~78% HBM
// duty). Pure register double-buffer (A/B), static indexing, no barriers.
// __launch_bounds__(256,2): 256-VGPR budget holds both 64-reg buffers.
// ---------------------------------------------------------------------------
__global__ __launch_bounds__(256, 2) void compact_kernel(
    const float* __restrict__ W, int* __restrict__ cIdx, float* __restrict__ cW) {
    const int wave = threadIdx.x >> 6;
    const int lane = threadIdx.x & 63;
    const int rbase = (blockIdx.x * 4 + wave) * 4;  // 4 rows per wave
    const unsigned long long lt = (1ull << lane) - 1ull;

    f32x4 A[16], B[16];

#define ISSUE(BUF, R) do {                                                    \
        const f32x4* row4 = reinterpret_cast<const f32x4*>(                   \
            W + (size_t)(rbase + (R)) * IN_DIM);                              \
        _Pragma("unroll")                                                     \
        for (int k = 0; k < 16; ++k)                                          \
            BUF[k] = __builtin_nontemporal_load(row4 + k * 64 + lane);        \
    } while (0)

    // Deterministic compaction: element order = ascending global index
    // (k*256 + lane*4 + c).
#define COMPACT(BUF, R) do {                                                  \
        int* __restrict__ rowIdx = cIdx + (size_t)(rbase + (R)) * 32;         \
        float* __restrict__ rowW = cW + (size_t)(rbase + (R)) * 32;           \
        int base = 0;                                                         \
        _Pragma("unroll")                                                     \
        for (int k = 0; k < 16; ++k) {                                        \
            float e[4] = {BUF[k].x, BUF[k].y, BUF[k].z, BUF[k].w};            \
            unsigned long long m[4];                                          \
            _Pragma("unroll")                                                 \
            for (int c = 0; c < 4; ++c) m[c] = __ballot(e[c] != 0.f);         \
            int below = 0;                                                    \
            _Pragma("unroll")                                                 \
            for (int c = 0; c < 4; ++c) below += __popcll(m[c] & lt);         \
            int myprev = 0;                                                   \
            _Pragma("unroll")                                                 \
            for (int c = 0; c < 4; ++c) {                                     \
                if (e[c] != 0.f) {                                            \
                    const int pos = base + below + myprev;                    \
                    if (pos < 32) {                                           \
                        rowIdx[pos] = ((k * 64 + lane) << 2) + c;             \
                        rowW[pos] = e[c];                                     \
                    }                                                         \
                    ++myprev;                                                 \
                }                                                             \
            }                                                                 \
            _Pragma("unroll")                                                 \
            for (int c = 0; c < 4; ++c) base += __popcll(m[c]);               \
        }                                                                     \
    } while (0)

    ISSUE(A, 0);
    ISSUE(B, 1);  COMPACT(A, 0);   // A's loads complete while B's fly
    ISSUE(A, 2);  COMPACT(B, 1);
    ISSUE(B, 3);  COMPACT(A, 2);
                  COMPACT(B, 3);
#undef ISSUE
#undef COMPACT
}

// ---------------------------------------------------------------------------
// Kernel 3: fused sparse dendrite + LeakyReLU + block-diagonal soma +
// LeakyReLU. One block per neuron, thread = batch column, 512 fully
// unrolled L2 gathers. (Unchanged from Round 2 — proven.)
// ---------------------------------------------------------------------------
__global__ __launch_bounds__(256) void neuron_kernel(
    const int* __restrict__ cIdx, const float* __restrict__ cW,
    const float* __restrict__ db, const float* __restrict__ sW,
    const float* __restrict__ sb, const float* __restrict__ xT,
    float* __restrict__ out) {
    const int bid = blockIdx.x;
    // XCD-chunked swizzle: 128 consecutive neurons per XCD.
    const int n = (bid & 7) * (N_NEURONS / 8) + (bid >> 3);
    const int t = threadIdx.x;

    __shared__ int   s_idx[512];
    __shared__ float s_w[512];
    __shared__ float s_sw[16];
    __shared__ float s_db[16];

    {
        const int* gi = cIdx + (size_t)n * 512;
        const float* gw = cW + (size_t)n * 512;
        s_idx[t]       = gi[t] << 8;        // pre-scale: idx * BATCH
        s_idx[t + 256] = gi[t + 256] << 8;
        s_w[t]         = gw[t];
        s_w[t + 256]   = gw[t + 256];
    }
    if (t < 16) {
        s_sw[t] = sW[(size_t)n * N_SOMA + n * 16 + t];
        s_db[t] = db[n * 16 + t];
    }
    __syncthreads();

    float sacc = sb[n];
#pragma unroll
    for (int r = 0; r < 16; ++r) {
        float dacc = s_db[r];
#pragma unroll
        for (int j = 0; j < 32; ++j) {
            dacc = fmaf(s_w[r * 32 + j], xT[(size_t)s_idx[r * 32 + j] + t], dacc);
        }
        dacc = (dacc >= 0.f) ? dacc : NEG_SLOPE * dacc;
        sacc = fmaf(s_sw[r], dacc, sacc);
    }
    sacc = (sacc >= 0.f) ? sacc : NEG_SLOPE * sacc;
    out[(size_t)t * N_NEURONS + n] = sacc;
}

// ---------------------------------------------------------------------------
extern "C" void kernel_launch(void* const* d_in, const int* in_sizes, int n_in,
                              void* d_out, int out_size, void* d_ws, size_t ws_size,
                              hipStream_t stream) {
    const float* x  = (const float*)d_in[0];  // [256][4096]
    const float* dW = (const float*)d_in[1];  // [16384][4096] (pre-masked)
    const float* db = (const float*)d_in[2];  // [16384]
    const float* sW = (const float*)d_in[3];  // [1024][16384] (pre-masked)
    const float* sb = (const float*)d_in[4];  // [1024]
    float* out = (float*)d_out;               // [256][1024]

    float* xT   = (float*)d_ws;                          // [4096][256]   4 MB
    int*   cIdx = (int*)(xT + (size_t)IN_DIM * BATCH);   // [16384][32]   2 MB
    float* cW   = (float*)(cIdx + (size_t)N_SOMA * 32);  // [16384][32]   2 MB

    transpose_x_kernel<<<dim3(IN_DIM / 64, BATCH / 64), 256, 0, stream>>>(x, xT);
    compact_kernel<<<N_SOMA / 16, 256, 0, stream>>>(dW, cIdx, cW);
    neuron_kernel<<<N_NEURONS, 256, 0, stream>>>(cIdx, cW, db, sW, sb, xT, out);
}